// Round 6
// baseline (588.264 us; speedup 1.0000x reference)
//
#include <hip/hip_runtime.h>
#include <stdint.h>

typedef unsigned short u16;
typedef __bf16 bf16x8 __attribute__((ext_vector_type(8)));
typedef float   f32x4 __attribute__((ext_vector_type(4)));
typedef u16     u16x8 __attribute__((ext_vector_type(8)));
typedef u16     u16x4 __attribute__((ext_vector_type(4)));

__device__ __forceinline__ u16 f2bf(float f) {
    union { float f; uint32_t i; } c; c.f = f;
    uint32_t r = c.i + 0x7FFFu + ((c.i >> 16) & 1u);   // RNE
    return (u16)(r >> 16);
}
// packed f32x2 -> bf16x2 (RNE), one VALU op. No builtin on gfx950 (T12 recipe).
__device__ __forceinline__ uint32_t cvt_pk_bf16(float lo, float hi) {
    uint32_t r;
    asm("v_cvt_pk_bf16_f32 %0, %1, %2" : "=v"(r) : "v"(lo), "v"(hi));
    return r;
}
// async global->LDS, 16B per lane. LDS dest must be wave-uniform base + lane*16.
__device__ __forceinline__ void gload_lds16(const u16* g, u16* l) {
    __builtin_amdgcn_global_load_lds(
        (__attribute__((address_space(1))) void*)(g),
        (__attribute__((address_space(3))) void*)(l), 16, 0, 0);
}
// Counted-vmcnt barrier (T4): wait until <=N VMEM ops outstanding, then
// s_barrier. "memory" clobber pins all LDS reads/writes and gload issues on
// either side. NEVER drains to 0 in steady state (the round-5 defect was
// __syncthreads' implicit vmcnt(0)).
template<int N>
__device__ __forceinline__ void wait_vm_barrier() {
    asm volatile("s_waitcnt vmcnt(%0)\n\ts_barrier" :: "n"(N) : "memory");
}

// ---------------- fp32 -> bf16 weight conversion: ONE dispatch, 6 segments ----
__global__ __launch_bounds__(256) void cvt_all(
    const float* __restrict__ wq, const float* __restrict__ wk,
    const float* __restrict__ wv, const float* __restrict__ wo,
    const float* __restrict__ w1, const float* __restrict__ w2,
    u16* __restrict__ wqb, u16* __restrict__ wkb, u16* __restrict__ wvb,
    u16* __restrict__ wob, u16* __restrict__ w1b, u16* __restrict__ w2b)
{
    int blk = blockIdx.x;
    const float* src; u16* dst; int off;
    if      (blk < 1024)  { src = wq; dst = wqb; off = blk; }
    else if (blk < 2048)  { src = wk; dst = wkb; off = blk - 1024; }
    else if (blk < 3072)  { src = wv; dst = wvb; off = blk - 2048; }
    else if (blk < 4096)  { src = wo; dst = wob; off = blk - 3072; }
    else if (blk < 8192)  { src = w1; dst = w1b; off = blk - 4096; }
    else                  { src = w2; dst = w2b; off = blk - 8192; }
    int i = off * 1024 + threadIdx.x * 4;
    float4 v = *(const float4*)(src + i);
    u16x4 o; o[0] = f2bf(v.x); o[1] = f2bf(v.y); o[2] = f2bf(v.z); o[3] = f2bf(v.w);
    *(u16x4*)(dst + i) = o;
}

// ---------------- LayerNorm: fp32 in -> bf16 out, one wave per row (D=1024) ----
__global__ __launch_bounds__(256) void ln_kernel(
    const float* __restrict__ x, const float* __restrict__ ga,
    const float* __restrict__ be, u16* __restrict__ out)
{
    const int D = 1024;
    int row  = blockIdx.x * 4 + (threadIdx.x >> 6);
    int lane = threadIdx.x & 63;
    const float* xr = x + (size_t)row * D + lane * 16;
    float f[16];
#pragma unroll
    for (int i = 0; i < 4; ++i) *(float4*)&f[i * 4] = *(const float4*)(xr + i * 4);
    float s = 0.f, s2 = 0.f;
#pragma unroll
    for (int i = 0; i < 16; ++i) { s += f[i]; s2 += f[i] * f[i]; }
#pragma unroll
    for (int off = 1; off < 64; off <<= 1) {
        s  += __shfl_xor(s,  off, 64);
        s2 += __shfl_xor(s2, off, 64);
    }
    float mean = s * (1.0f / 1024.0f);
    float var  = s2 * (1.0f / 1024.0f) - mean * mean;
    var = var < 0.f ? 0.f : var;
    float inv = 1.0f / sqrtf(var + 1e-6f);
    float g[16], b[16];
#pragma unroll
    for (int i = 0; i < 4; ++i) {
        *(float4*)&g[i * 4] = *(const float4*)(ga + lane * 16 + i * 4);
        *(float4*)&b[i * 4] = *(const float4*)(be + lane * 16 + i * 4);
    }
    u16x8 o0, o1;
#pragma unroll
    for (int i = 0; i < 8; ++i) {
        o0[i] = f2bf(g[i]     * (f[i]     - mean) * inv + b[i]);
        o1[i] = f2bf(g[8 + i] * (f[8 + i] - mean) * inv + b[8 + i]);
    }
    u16* orow = out + (size_t)row * D + lane * 16;
    *(u16x8*)(orow)     = o0;
    *(u16x8*)(orow + 8) = o1;
}

// ===== 4-buffer ring GEMM cores, BK=32, counted vmcnt (T4) =====================
// Iteration t: [issue step t+3's DMAs] -> [ds_read frags of buf t&3 + MFMA]
// -> wait_vm_barrier<loads_per_step * steps_in_flight_beyond_t+1>.
// Steady state leaves 2 steps (8 or 6 loads) in flight across the barrier.
// WAR: buf (t+3)&3 == buf (t-1)&3, whose reads retired at the end-of-(t-1)
// barrier before iteration t issues any write to it.
// Tail peel (derived, not guessed): at end of iter t the newer-than-(t+1)
// outstanding loads number L*(min(nk-1,t+3)-(t+1)) -> waits L*2, L*1, 0.

// ------- 256x256-tile ring core (512 thr, 8 waves 2Mx4N, acc[8][4]) -----------
// Buffer = 32KB: A[r0-127]@0 A[r128-255]@4096 B[r0-127]@8192 B[r128-255]@12288
// (elem offsets; [128][32] k-planes, lane-linear DMA dest, frag reads cover a
// contiguous 1KB per wave = minimum 8-cy b128 pattern, conflict-free.)
__device__ __forceinline__ void gemm_ring256_core(
    const u16* __restrict__ A, const u16* __restrict__ W,
    int K, int ldw, int row_a0, int row_w0,
    u16* smem, f32x4 (&acc)[8][4])
{
    int tid  = threadIdx.x;
    int lane = tid & 63;
    int quad = lane >> 4, l16 = lane & 15;
    int wave = tid >> 6;
    int wm = wave >> 2, wn = wave & 3;         // 2M x 4N wave grid

    int srow = tid >> 2, scol = (tid & 3) * 8;
    const u16* a0 = A + (size_t)(row_a0 + srow) * K + scol;
    const u16* a1 = a0 + (size_t)128 * K;
    const u16* b0 = W + (size_t)(row_w0 + srow) * ldw + scol;
    const u16* b1 = b0 + (size_t)128 * ldw;
    u16* dst = smem + tid * 8;
    const int nk = K >> 5;                     // BK=32; K >= 128 assumed

    // prologue: stage steps 0,1,2 (12 loads, issue order = step order)
#pragma unroll
    for (int s = 0; s < 3; ++s) {
        u16* d = dst + s * 16384;
        const int k = s * 32;
        gload_lds16(a0 + k, d);
        gload_lds16(a1 + k, d + 4096);
        gload_lds16(b0 + k, d + 8192);
        gload_lds16(b1 + k, d + 12288);
    }
    const int abase = wm * 4096 + l16 * 32 + quad * 8;                       // + mt*512
    const int bbase = 8192 + (wn >> 1) * 4096 + ((wn & 1) * 64 + l16) * 32 + quad * 8; // + nt*512

    wait_vm_barrier<8>();                      // step 0 landed; 1,2 in flight

    for (int t = 0; t < nk; ++t) {
        if (t + 3 < nk) {                      // issue step t+3 into buf (t+3)&3
            u16* d = dst + ((t + 3) & 3) * 16384;
            const int k = (t + 3) * 32;
            gload_lds16(a0 + k, d);
            gload_lds16(a1 + k, d + 4096);
            gload_lds16(b0 + k, d + 8192);
            gload_lds16(b1 + k, d + 12288);
        }
        const u16* buf = smem + (t & 3) * 16384;
        bf16x8 af[8], bf[4];
#pragma unroll
        for (int mt = 0; mt < 8; ++mt)
            af[mt] = *(const bf16x8*)(&buf[abase + mt * 512]);
#pragma unroll
        for (int nt = 0; nt < 4; ++nt)
            bf[nt] = *(const bf16x8*)(&buf[bbase + nt * 512]);
#pragma unroll
        for (int mt = 0; mt < 8; ++mt)
#pragma unroll
            for (int nt = 0; nt < 4; ++nt)
                acc[mt][nt] = __builtin_amdgcn_mfma_f32_16x16x32_bf16(
                    af[mt], bf[nt], acc[mt][nt], 0, 0, 0);
        if      (t + 3 < nk) wait_vm_barrier<8>();
        else if (t + 2 < nk) wait_vm_barrier<4>();
        else if (t + 1 < nk) wait_vm_barrier<0>();
    }
}

// ------- 128x256-tile ring core (512 thr, 8 waves 2Mx4N, acc[4][4]) -----------
// Buffer = 24KB: A[128 rows]@0 | B[r0-127]@4096 | B[r128-255]@8192. 3 loads/step.
__device__ __forceinline__ void gemm_ring128_core(
    const u16* __restrict__ A, const u16* __restrict__ W,
    int K, int ldw, int row_a0, int row_w0,
    u16* smem, f32x4 (&acc)[4][4])
{
    int tid  = threadIdx.x;
    int lane = tid & 63;
    int quad = lane >> 4, l16 = lane & 15;
    int wave = tid >> 6;
    int wm = wave >> 2, wn = wave & 3;

    int srow = tid >> 2, scol = (tid & 3) * 8;
    const u16* a0 = A + (size_t)(row_a0 + srow) * K + scol;
    const u16* b0 = W + (size_t)(row_w0 + srow) * ldw + scol;
    const u16* b1 = b0 + (size_t)128 * ldw;
    u16* dst = smem + tid * 8;
    const int nk = K >> 5;

#pragma unroll
    for (int s = 0; s < 3; ++s) {
        u16* d = dst + s * 12288;
        const int k = s * 32;
        gload_lds16(a0 + k, d);
        gload_lds16(b0 + k, d + 4096);
        gload_lds16(b1 + k, d + 8192);
    }
    const int abase = (wm * 64 + l16) * 32 + quad * 8;                       // + mt*512
    const int bbase = 4096 + (wn >> 1) * 4096 + ((wn & 1) * 64 + l16) * 32 + quad * 8; // + nt*512

    wait_vm_barrier<6>();

    for (int t = 0; t < nk; ++t) {
        if (t + 3 < nk) {
            u16* d = dst + ((t + 3) & 3) * 12288;
            const int k = (t + 3) * 32;
            gload_lds16(a0 + k, d);
            gload_lds16(b0 + k, d + 4096);
            gload_lds16(b1 + k, d + 8192);
        }
        const u16* buf = smem + (t & 3) * 12288;
        bf16x8 af[4], bf[4];
#pragma unroll
        for (int mt = 0; mt < 4; ++mt)
            af[mt] = *(const bf16x8*)(&buf[abase + mt * 512]);
#pragma unroll
        for (int nt = 0; nt < 4; ++nt)
            bf[nt] = *(const bf16x8*)(&buf[bbase + nt * 512]);
#pragma unroll
        for (int mt = 0; mt < 4; ++mt)
#pragma unroll
            for (int nt = 0; nt < 4; ++nt)
                acc[mt][nt] = __builtin_amdgcn_mfma_f32_16x16x32_bf16(
                    af[mt], bf[nt], acc[mt][nt], 0, 0, 0);
        if      (t + 3 < nk) wait_vm_barrier<6>();
        else if (t + 2 < nk) wait_vm_barrier<3>();
        else if (t + 1 < nk) wait_vm_barrier<0>();
    }
}

// Generic 256^2 epilogue variant (bias/relu/resid), bf16 or fp32 out.
template<bool OUTF32>
__global__ __launch_bounds__(512, 2) void gemm256sq(
    const u16* __restrict__ A, const u16* __restrict__ W,
    const float* __restrict__ bias, const float* __restrict__ resid,
    void* __restrict__ Cp, int M, int N, int K, int ldw, int do_relu)
{
    __shared__ u16 smem[65536];                 // 128 KB: 4 x 32KB ring
    int tid  = threadIdx.x;
    int lane = tid & 63, wave = tid >> 6;
    int quad = lane >> 4, l16 = lane & 15;
    int wm = wave >> 2, wn = wave & 3;
    const int row_a0 = blockIdx.x * 256, row_w0 = blockIdx.y * 256;
    f32x4 acc[8][4] = {};
    gemm_ring256_core(A, W, K, ldw, row_a0, row_w0, smem, acc);
#pragma unroll
    for (int mt = 0; mt < 8; ++mt) {
#pragma unroll
        for (int nt = 0; nt < 4; ++nt) {
#pragma unroll
            for (int r = 0; r < 4; ++r) {
                int grow = row_a0 + wm * 128 + mt * 16 + quad * 4 + r;
                int gcol = row_w0 + wn * 64 + nt * 16 + l16;
                float vv = acc[mt][nt][r];
                if (bias)    vv += bias[gcol];
                if (do_relu) vv = vv > 0.f ? vv : 0.f;
                if (resid)   vv += resid[(size_t)grow * N + gcol];
                if (OUTF32) ((float*)Cp)[(size_t)grow * N + gcol] = vv;
                else        ((u16*)Cp)[(size_t)grow * N + gcol] = f2bf(vv);
            }
        }
    }
}

// QKV-fused 256^2 variant: W stacked [3072 x 1024]; BN=256 divides 1024.
__global__ __launch_bounds__(512, 2) void gemm256sq_qkv(
    const u16* __restrict__ A, const u16* __restrict__ Wqkv,
    u16* __restrict__ qo, u16* __restrict__ ko, u16* __restrict__ vo, int K)
{
    __shared__ u16 smem[65536];
    int tid  = threadIdx.x;
    int lane = tid & 63, wave = tid >> 6;
    int quad = lane >> 4, l16 = lane & 15;
    int wm = wave >> 2, wn = wave & 3;
    const int row_a0 = blockIdx.x * 256, row_w0 = blockIdx.y * 256;
    f32x4 acc[8][4] = {};
    gemm_ring256_core(A, Wqkv, K, K, row_a0, row_w0, smem, acc);
    int seg = row_w0 >> 10;
    u16* dst = (seg == 0) ? qo : (seg == 1) ? ko : vo;
    int col0 = row_w0 & 1023;
#pragma unroll
    for (int mt = 0; mt < 8; ++mt) {
#pragma unroll
        for (int nt = 0; nt < 4; ++nt) {
#pragma unroll
            for (int r = 0; r < 4; ++r) {
                int grow = row_a0 + wm * 128 + mt * 16 + quad * 4 + r;
                int gcol = col0 + wn * 64 + nt * 16 + l16;
                dst[(size_t)grow * 1024 + gcol] = f2bf(acc[mt][nt][r]);
            }
        }
    }
}

// 128x256 epilogue variant for N=1024 shapes (grid 64x4 = exact full round).
template<bool OUTF32>
__global__ __launch_bounds__(512, 2) void gemm128x256(
    const u16* __restrict__ A, const u16* __restrict__ W,
    const float* __restrict__ bias, const float* __restrict__ resid,
    void* __restrict__ Cp, int M, int N, int K, int ldw, int do_relu)
{
    __shared__ u16 smem[49152];                 // 96 KB: 4 x 24KB ring
    int tid  = threadIdx.x;
    int lane = tid & 63, wave = tid >> 6;
    int quad = lane >> 4, l16 = lane & 15;
    int wm = wave >> 2, wn = wave & 3;
    const int row_a0 = blockIdx.x * 128, row_w0 = blockIdx.y * 256;
    f32x4 acc[4][4] = {};
    gemm_ring128_core(A, W, K, ldw, row_a0, row_w0, smem, acc);
#pragma unroll
    for (int mt = 0; mt < 4; ++mt) {
#pragma unroll
        for (int nt = 0; nt < 4; ++nt) {
#pragma unroll
            for (int r = 0; r < 4; ++r) {
                int grow = row_a0 + wm * 64 + mt * 16 + quad * 4 + r;
                int gcol = row_w0 + wn * 64 + nt * 16 + l16;
                float vv = acc[mt][nt][r];
                if (bias)    vv += bias[gcol];
                if (do_relu) vv = vv > 0.f ? vv : 0.f;
                if (resid)   vv += resid[(size_t)grow * N + gcol];
                if (OUTF32) ((float*)Cp)[(size_t)grow * N + gcol] = vv;
                else        ((u16*)Cp)[(size_t)grow * N + gcol] = f2bf(vv);
            }
        }
    }
}

// -------- MFMA flash attention v4: 32 q-rows/wave, 256-q blocks ---------------
// (unchanged — control; LDS-BW-bound, 131.5 us, conflicts 1.055e7)
__global__ __launch_bounds__(512, 4) void attn_kernel(
    const u16* __restrict__ Q, const u16* __restrict__ Km, const u16* __restrict__ Vm,
    const int* __restrict__ mask, u16* __restrict__ O)
{
    const int S = 2048, DM = 1024;
    const float C1 = 0.18033688f;      // 0.125 * log2(e)
    const float C0 = -11.541560f;      // -8 * log2(e)
    __shared__ u16 smem[35840];        // 71,680 B -> 2 blocks/CU
    u16* Ks0 = smem;                   // [64*64] swizzled 16B chunks
    u16* Ks1 = smem + 4096;
    u16* Vt0 = smem + 8192;            // [64][72]
    u16* Vt1 = smem + 12800;
    u16* Ps  = smem + 17408;           // [256][72] wave-private rows
    u16* Qs  = smem + 17408;           // alias: Qs dead before Ps written

    int qt = blockIdx.x, bh = blockIdx.y;
    int b = bh >> 4, h = bh & 15;
    int tid = threadIdx.x;
    int wave = tid >> 6, lane = tid & 63;
    int quad = lane >> 4, l16 = lane & 15;
    size_t base = (size_t)b * S;
    size_t hoff = (size_t)h * 64;

    {   // stage Q tile [256 q][64 d]: 32 u16 per thread
        int r = tid >> 1, c0 = (tid & 1) * 32;
        const u16* src = Q + (base + qt * 256 + r) * DM + hoff + c0;
        u16* dq = Qs + r * 72 + c0;
        *(u16x8*)(dq)      = *(const u16x8*)(src);
        *(u16x8*)(dq + 8)  = *(const u16x8*)(src + 8);
        *(u16x8*)(dq + 16) = *(const u16x8*)(src + 16);
        *(u16x8*)(dq + 24) = *(const u16x8*)(src + 24);
    }
    const u16* ksrc = Km + (base + (tid >> 3)) * DM + hoff
                    + ((tid & 7) ^ ((tid >> 5) & 7)) * 8;
    int kp = tid & 31, d0 = (tid >> 5) * 4;
    const u16* vsrc = Vm + (base + kp * 2) * DM + hoff + d0;
    const int* msrc = mask + b * S + 4 * l16;

    __syncthreads();
    const int q0 = wave * 32;
    bf16x8 qf00 = *(const bf16x8*)(&Qs[(q0 + l16) * 72 + quad * 8]);
    bf16x8 qf01 = *(const bf16x8*)(&Qs[(q0 + l16) * 72 + 32 + quad * 8]);
    bf16x8 qf10 = *(const bf16x8*)(&Qs[(q0 + 16 + l16) * 72 + quad * 8]);
    bf16x8 qf11 = *(const bf16x8*)(&Qs[(q0 + 16 + l16) * 72 + 32 + quad * 8]);
    const int swz = (l16 & 7) * 8;
    const int u0  = (quad * 8) ^ swz;

    {   // prologue: stage tile 0 into Ks0/Vt0
        u16x4 va = *(const u16x4*)(vsrc);
        u16x4 vb = *(const u16x4*)(vsrc + DM);
        gload_lds16(ksrc, Ks0 + tid * 8);
        ksrc += 64 * DM; vsrc += 64 * DM;
#pragma unroll
        for (int i = 0; i < 4; ++i) {
            uint32_t w = (uint32_t)va[i] | ((uint32_t)vb[i] << 16);
            *(uint32_t*)(&Vt0[(d0 + i) * 72 + kp * 2]) = w;
        }
    }
    __syncthreads();

    float l0[4] = {0.f, 0.f, 0.f, 0.f};
    float l1[4] = {0.f, 0.f, 0.f, 0.f};
    f32x4 o0[4] = {}, o1[4] = {};

    for (int it = 0; it < 32; ++it) {
        const u16* Kcur = (it & 1) ? Ks1 : Ks0;
        const u16* Vcur = (it & 1) ? Vt1 : Vt0;
        u16* Knxt = (it & 1) ? Ks0 : Ks1;
        u16* Vnxt = (it & 1) ? Vt0 : Vt1;
        const bool pfch = (it < 31);
        u16x4 va, vb;
        if (pfch) {
            va = *(const u16x4*)(vsrc);
            vb = *(const u16x4*)(vsrc + DM);
            gload_lds16(ksrc, Knxt + tid * 8);
            ksrc += 64 * DM; vsrc += 64 * DM;
        }
        f32x4 s0[4] = {}, s1[4] = {};
#pragma unroll
        for (int t = 0; t < 4; ++t) {
            const u16* krp = Kcur + (4 * l16 + t) * 64;
            bf16x8 kf0 = *(const bf16x8*)(krp + u0);
            bf16x8 kf1 = *(const bf16x8*)(krp + (u0 ^ 32));
            s0[t] = __builtin_amdgcn_mfma_f32_16x16x32_bf16(qf00, kf0, s0[t], 0, 0, 0);
            s0[t] = __builtin_amdgcn_mfma_f32_16x16x32_bf16(qf01, kf1, s0[t], 0, 0, 0);
            s1[t] = __builtin_amdgcn_mfma_f32_16x16x32_bf16(qf10, kf0, s1[t], 0, 0, 0);
            s1[t] = __builtin_amdgcn_mfma_f32_16x16x32_bf16(qf11, kf1, s1[t], 0, 0, 0);
        }
        int4 mk4 = *(const int4*)(msrc); msrc += 64;
        float c0t[4];
        c0t[0] = (mk4.x == 0) ? -1e38f : C0;
        c0t[1] = (mk4.y == 0) ? -1e38f : C0;
        c0t[2] = (mk4.z == 0) ? -1e38f : C0;
        c0t[3] = (mk4.w == 0) ? -1e38f : C0;
#pragma unroll
        for (int r = 0; r < 4; ++r) {
            float p0 = exp2f(fmaf(s0[0][r], C1, c0t[0]));
            float p1 = exp2f(fmaf(s0[1][r], C1, c0t[1]));
            float p2 = exp2f(fmaf(s0[2][r], C1, c0t[2]));
            float p3 = exp2f(fmaf(s0[3][r], C1, c0t[3]));
            l0[r] += (p0 + p1) + (p2 + p3);
            uint2 pw;
            pw.x = cvt_pk_bf16(p0, p1);
            pw.y = cvt_pk_bf16(p2, p3);
            *(uint2*)(&Ps[(q0 + quad * 4 + r) * 72 + 4 * l16]) = pw;
        }
#pragma unroll
        for (int r = 0; r < 4; ++r) {
            float p0 = exp2f(fmaf(s1[0][r], C1, c0t[0]));
            float p1 = exp2f(fmaf(s1[1][r], C1, c0t[1]));
            float p2 = exp2f(fmaf(s1[2][r], C1, c0t[2]));
            float p3 = exp2f(fmaf(s1[3][r], C1, c0t[3]));
            l1[r] += (p0 + p1) + (p2 + p3);
            uint2 pw;
            pw.x = cvt_pk_bf16(p0, p1);
            pw.y = cvt_pk_bf16(p2, p3);
            *(uint2*)(&Ps[(q0 + 16 + quad * 4 + r) * 72 + 4 * l16]) = pw;
        }
        bf16x8 pf00 = *(const bf16x8*)(&Ps[(q0 + l16) * 72 + quad * 8]);
        bf16x8 pf01 = *(const bf16x8*)(&Ps[(q0 + l16) * 72 + 32 + quad * 8]);
        bf16x8 pf10 = *(const bf16x8*)(&Ps[(q0 + 16 + l16) * 72 + quad * 8]);
        bf16x8 pf11 = *(const bf16x8*)(&Ps[(q0 + 16 + l16) * 72 + 32 + quad * 8]);
#pragma unroll
        for (int t = 0; t < 4; ++t) {
            bf16x8 vf0 = *(const bf16x8*)(&Vcur[(t * 16 + l16) * 72 + quad * 8]);
            bf16x8 vf1 = *(const bf16x8*)(&Vcur[(t * 16 + l16) * 72 + 32 + quad * 8]);
            o0[t] = __builtin_amdgcn_mfma_f32_16x16x32_bf16(pf00, vf0, o0[t], 0, 0, 0);
            o0[t] = __builtin_amdgcn_mfma_f32_16x16x32_bf16(pf01, vf1, o0[t], 0, 0, 0);
            o1[t] = __builtin_amdgcn_mfma_f32_16x16x32_bf16(pf10, vf0, o1[t], 0, 0, 0);
            o1[t] = __builtin_amdgcn_mfma_f32_16x16x32_bf16(pf11, vf1, o1[t], 0, 0, 0);
        }
        if (pfch) {
#pragma unroll
            for (int i = 0; i < 4; ++i) {
                uint32_t w = (uint32_t)va[i] | ((uint32_t)vb[i] << 16);
                *(uint32_t*)(&Vnxt[(d0 + i) * 72 + kp * 2]) = w;
            }
        }
        __syncthreads();
    }
#pragma unroll
    for (int r = 0; r < 4; ++r) {
#pragma unroll
        for (int off = 1; off < 16; off <<= 1) {
            l0[r] += __shfl_xor(l0[r], off, 16);
            l1[r] += __shfl_xor(l1[r], off, 16);
        }
        float i0 = 1.0f / l0[r];
        float i1 = 1.0f / l1[r];
        u16* dst0 = O + (base + qt * 256 + q0 + quad * 4 + r) * DM + hoff + l16;
        u16* dst1 = dst0 + (size_t)16 * DM;
#pragma unroll
        for (int t = 0; t < 4; ++t) {
            dst0[t * 16] = f2bf(o0[t][r] * i0);
            dst1[t * 16] = f2bf(o1[t][r] * i1);
        }
    }
}

// -------------------------------------------------------------------------------
// Workspace budget: 72 MB (proven). ws[0..6)MB wq|wk|wv stacked; ws[6..8) wo;
// ws[8..24) w1,w2; ws[24..40) xn; ws[40..56) q; ws[40..72) hb.
// d_out doubles as k/v (bf16) then x1 (fp32).
extern "C" void kernel_launch(void* const* d_in, const int* in_sizes, int n_in,
                              void* d_out, int out_size, void* d_ws, size_t ws_size,
                              hipStream_t stream)
{
    (void)in_sizes; (void)n_in; (void)out_size; (void)ws_size;
    const float* x    = (const float*)d_in[0];
    const int*   mask = (const int*)d_in[1];
    const float* wq   = (const float*)d_in[2];
    const float* wk   = (const float*)d_in[3];
    const float* wv   = (const float*)d_in[4];
    const float* wo   = (const float*)d_in[5];
    const float* ln1a = (const float*)d_in[6];
    const float* ln1b = (const float*)d_in[7];
    const float* ln2a = (const float*)d_in[8];
    const float* ln2b = (const float*)d_in[9];
    const float* w1   = (const float*)d_in[10];
    const float* b1   = (const float*)d_in[11];
    const float* w2   = (const float*)d_in[12];
    const float* b2   = (const float*)d_in[13];

    const int M = 8192, D = 1024, F = 4096;
    char* ws = (char*)d_ws;
    u16*  wqkv = (u16*)(ws);                  // stacked 3072x1024
    u16*  wqb = wqkv;
    u16*  wkb = (u16*)(ws + (2u  << 20));
    u16*  wvb = (u16*)(ws + (4u  << 20));
    u16*  wob = (u16*)(ws + (6u  << 20));
    u16*  w1b = (u16*)(ws + (8u  << 20));
    u16*  w2b = (u16*)(ws + (16u << 20));
    u16*  xn  = (u16*)(ws + (24u << 20));     // xn1 / attn_out / xn2
    u16*  q   = (u16*)(ws + (40u << 20));
    u16*  hb  = (u16*)(ws + (40u << 20));     // overlaps q (q dead by FF1)

    u16*   kbuf = (u16*)d_out;
    u16*   vbuf = (u16*)d_out + (size_t)M * D;
    float* x1   = (float*)d_out;

    cvt_all<<<12288, 256, 0, stream>>>(wq, wk, wv, wo, w1, w2,
                                       wqb, wkb, wvb, wob, w1b, w2b);

    ln_kernel<<<M / 4, 256, 0, stream>>>(x, ln1a, ln1b, xn);
    dim3 gq(M / 256, 3072 / 256);             // 32 x 12 = 384 blocks
    gemm256sq_qkv<<<gq, 512, 0, stream>>>(xn, wqkv, q, kbuf, vbuf, D);
    dim3 ga(2048 / 256, 64);
    attn_kernel<<<ga, 512, 0, stream>>>(q, kbuf, vbuf, mask, xn);
    dim3 g1(M / 128, D / 256);                // 64 x 4 = 256 (1 full round)
    gemm128x256<true ><<<g1, 512, 0, stream>>>(xn, wob, nullptr, x, x1, M, D, D, D, 0);
    ln_kernel<<<M / 4, 256, 0, stream>>>(x1, ln2a, ln2b, xn);
    dim3 gf1(M / 256, 2048 / 256);            // 32 x 8 = 256 (1 full round)
    dim3 gf2(M / 128, D / 256);               // 64 x 4 = 256
    gemm256sq<false><<<gf1, 512, 0, stream>>>(xn, w1b, b1, nullptr, hb, M, 2048, D, D, 1);
    gemm128x256<true ><<<gf2, 512, 0, stream>>>(hb, w2b, nullptr, x1, x1, M, D, 2048, F, 0);
    gemm256sq<false><<<gf1, 512, 0, stream>>>(xn, w1b + (size_t)2048 * D, b1 + 2048, nullptr, hb, M, 2048, D, D, 1);
    gemm128x256<true ><<<gf2, 512, 0, stream>>>(hb, w2b + 2048, b2, x1, x1, M, D, 2048, F, 0);
}

// Round 7
// 561.804 us; speedup vs baseline: 1.0471x; 1.0471x over previous
//
#include <hip/hip_runtime.h>
#include <stdint.h>

typedef unsigned short u16;
typedef __bf16 bf16x8 __attribute__((ext_vector_type(8)));
typedef float   f32x4 __attribute__((ext_vector_type(4)));
typedef u16     u16x8 __attribute__((ext_vector_type(8)));
typedef u16     u16x4 __attribute__((ext_vector_type(4)));

__device__ __forceinline__ u16 f2bf(float f) {
    union { float f; uint32_t i; } c; c.f = f;
    uint32_t r = c.i + 0x7FFFu + ((c.i >> 16) & 1u);   // RNE
    return (u16)(r >> 16);
}
// packed f32x2 -> bf16x2 (RNE), one VALU op. No builtin on gfx950 (T12 recipe).
__device__ __forceinline__ uint32_t cvt_pk_bf16(float lo, float hi) {
    uint32_t r;
    asm("v_cvt_pk_bf16_f32 %0, %1, %2" : "=v"(r) : "v"(lo), "v"(hi));
    return r;
}
// async global->LDS, 16B per lane. LDS dest must be wave-uniform base + lane*16.
__device__ __forceinline__ void gload_lds16(const u16* g, u16* l) {
    __builtin_amdgcn_global_load_lds(
        (__attribute__((address_space(1))) void*)(g),
        (__attribute__((address_space(3))) void*)(l), 16, 0, 0);
}
// Counted-vmcnt barrier (T4): wait until <=N VMEM ops outstanding, then
// s_barrier. "memory" clobber pins LDS ops and gload issues on either side.
template<int N>
__device__ __forceinline__ void wait_vm_barrier() {
    asm volatile("s_waitcnt vmcnt(%0)\n\ts_barrier" :: "n"(N) : "memory");
}

// ---------------- fp32 -> bf16 weight conversion: ONE dispatch, 6 segments ----
__global__ __launch_bounds__(256) void cvt_all(
    const float* __restrict__ wq, const float* __restrict__ wk,
    const float* __restrict__ wv, const float* __restrict__ wo,
    const float* __restrict__ w1, const float* __restrict__ w2,
    u16* __restrict__ wqb, u16* __restrict__ wkb, u16* __restrict__ wvb,
    u16* __restrict__ wob, u16* __restrict__ w1b, u16* __restrict__ w2b)
{
    int blk = blockIdx.x;
    const float* src; u16* dst; int off;
    if      (blk < 1024)  { src = wq; dst = wqb; off = blk; }
    else if (blk < 2048)  { src = wk; dst = wkb; off = blk - 1024; }
    else if (blk < 3072)  { src = wv; dst = wvb; off = blk - 2048; }
    else if (blk < 4096)  { src = wo; dst = wob; off = blk - 3072; }
    else if (blk < 8192)  { src = w1; dst = w1b; off = blk - 4096; }
    else                  { src = w2; dst = w2b; off = blk - 8192; }
    int i = off * 1024 + threadIdx.x * 4;
    float4 v = *(const float4*)(src + i);
    u16x4 o; o[0] = f2bf(v.x); o[1] = f2bf(v.y); o[2] = f2bf(v.z); o[3] = f2bf(v.w);
    *(u16x4*)(dst + i) = o;
}

// ---------------- LayerNorm: fp32 in -> bf16 out, one wave per row (D=1024) ----
__global__ __launch_bounds__(256) void ln_kernel(
    const float* __restrict__ x, const float* __restrict__ ga,
    const float* __restrict__ be, u16* __restrict__ out)
{
    const int D = 1024;
    int row  = blockIdx.x * 4 + (threadIdx.x >> 6);
    int lane = threadIdx.x & 63;
    const float* xr = x + (size_t)row * D + lane * 16;
    float f[16];
#pragma unroll
    for (int i = 0; i < 4; ++i) *(float4*)&f[i * 4] = *(const float4*)(xr + i * 4);
    float s = 0.f, s2 = 0.f;
#pragma unroll
    for (int i = 0; i < 16; ++i) { s += f[i]; s2 += f[i] * f[i]; }
#pragma unroll
    for (int off = 1; off < 64; off <<= 1) {
        s  += __shfl_xor(s,  off, 64);
        s2 += __shfl_xor(s2, off, 64);
    }
    float mean = s * (1.0f / 1024.0f);
    float var  = s2 * (1.0f / 1024.0f) - mean * mean;
    var = var < 0.f ? 0.f : var;
    float inv = 1.0f / sqrtf(var + 1e-6f);
    float g[16], b[16];
#pragma unroll
    for (int i = 0; i < 4; ++i) {
        *(float4*)&g[i * 4] = *(const float4*)(ga + lane * 16 + i * 4);
        *(float4*)&b[i * 4] = *(const float4*)(be + lane * 16 + i * 4);
    }
    u16x8 o0, o1;
#pragma unroll
    for (int i = 0; i < 8; ++i) {
        o0[i] = f2bf(g[i]     * (f[i]     - mean) * inv + b[i]);
        o1[i] = f2bf(g[8 + i] * (f[8 + i] - mean) * inv + b[8 + i]);
    }
    u16* orow = out + (size_t)row * D + lane * 16;
    *(u16x8*)(orow)     = o0;
    *(u16x8*)(orow + 8) = o1;
}

// ===== 128x128-tile 3-ring GEMM, 2 blocks/CU, counted vmcnt ===================
// Round 4-6 post-mortem: three schedules x three tile shapes all pinned at
// ~477 TF, ALL at 1 block/CU — during each block's barrier convoy the CU is
// empty. The untested quadrant is counted-vmcnt ring x >=2 resident blocks
// (m114 cross-block wave overlap). This kernel: 48KB LDS (3 x 16KB ring),
// __launch_bounds__(512,4) -> VGPR<=128 -> exactly 2 blocks/CU (16 waves).
// BN=128 makes every grid an exact multiple of the 512-block residency:
// QKV 1536 (3 rounds), FF1 1024 (2), FF2/WO 512 (1). 2 loads/thread/step.
// Ring: issue step t+2 at iter top into buf (t+2)%3 (== buf (t-1)%3, reads
// retired at prev trailing barrier); compute buf t%3; trailing vmcnt(2)
// drains step t+1 only (2 loads/step x 1 step beyond t+1); tail peel 2->0.
// Per 16KB buffer (8192 u16): A [128][32] @0 | B [128][32] @4096
// (lane-linear DMA dest; frag reads stride 64B rows -> 2-way-free).
__device__ __forceinline__ void gemm128q_core(
    const u16* __restrict__ A, const u16* __restrict__ W,
    int K, int ldw, int row_a0, int row_w0,
    u16* smem, f32x4 (&acc)[4][2])
{
    int tid  = threadIdx.x;
    int lane = tid & 63;
    int quad = lane >> 4, l16 = lane & 15;
    int wave = tid >> 6;
    int wm = wave >> 2, wn = wave & 3;         // 2M x 4N; wave tile 64x32

    const u16* a0 = A + (size_t)(row_a0 + (tid >> 2)) * K   + (tid & 3) * 8;
    const u16* b0 = W + (size_t)(row_w0 + (tid >> 2)) * ldw + (tid & 3) * 8;
    u16* dst = smem + tid * 8;
    const int nk = K >> 5;                     // BK=32

    // prologue: stage steps 0,1,2 (6 loads); wait<4> drains step 0 only
#pragma unroll
    for (int s = 0; s < 3; ++s) {
        gload_lds16(a0 + s * 32, dst + s * 8192);
        gload_lds16(b0 + s * 32, dst + s * 8192 + 4096);
    }
    const int abase = (wm * 64 + l16) * 32 + quad * 8;          // + mt*512
    const int bbase = 4096 + (wn * 32 + l16) * 32 + quad * 8;   // + nt*512
    wait_vm_barrier<4>();

    int cb = 0, nb = 16384;                    // buf t%3, buf (t+2)%3 (u16 elems)
    for (int t = 0; t < nk; ++t) {
        if (t + 2 < nk) {                      // issue step t+2
            gload_lds16(a0 + (t + 2) * 32, dst + nb);
            gload_lds16(b0 + (t + 2) * 32, dst + nb + 4096);
        }
        const u16* buf = smem + cb;
        bf16x8 af[4], bf[2];
#pragma unroll
        for (int mt = 0; mt < 4; ++mt)
            af[mt] = *(const bf16x8*)(&buf[abase + mt * 512]);
#pragma unroll
        for (int nt = 0; nt < 2; ++nt)
            bf[nt] = *(const bf16x8*)(&buf[bbase + nt * 512]);
#pragma unroll
        for (int mt = 0; mt < 4; ++mt)
#pragma unroll
            for (int nt = 0; nt < 2; ++nt)
                acc[mt][nt] = __builtin_amdgcn_mfma_f32_16x16x32_bf16(
                    af[mt], bf[nt], acc[mt][nt], 0, 0, 0);
        if      (t + 2 < nk) wait_vm_barrier<2>();
        else if (t + 1 < nk) wait_vm_barrier<0>();
        cb = (cb == 16384) ? 0 : cb + 8192;    // (t+1)%3 * 8192
        nb = (nb == 16384) ? 0 : nb + 8192;    // (t+3)%3 * 8192
    }
}

// Generic epilogue variant: C = f(A@W^T + bias) (+resid), fp32 or bf16 out.
template<bool OUTF32>
__global__ __launch_bounds__(512, 4) void gemm128q(
    const u16* __restrict__ A, const u16* __restrict__ W,
    const float* __restrict__ bias, const float* __restrict__ resid,
    void* __restrict__ Cp, int M, int N, int K, int ldw, int do_relu)
{
    __shared__ u16 smem[24576];                 // 48 KB: 3 x 16KB ring
    int tid  = threadIdx.x;
    int lane = tid & 63, wave = tid >> 6;
    int quad = lane >> 4, l16 = lane & 15;
    int wm = wave >> 2, wn = wave & 3;
    const int row_a0 = blockIdx.x * 128, row_w0 = blockIdx.y * 128;
    f32x4 acc[4][2] = {};
    gemm128q_core(A, W, K, ldw, row_a0, row_w0, smem, acc);
#pragma unroll
    for (int mt = 0; mt < 4; ++mt) {
#pragma unroll
        for (int nt = 0; nt < 2; ++nt) {
#pragma unroll
            for (int r = 0; r < 4; ++r) {
                int grow = row_a0 + wm * 64 + mt * 16 + quad * 4 + r;
                int gcol = row_w0 + wn * 32 + nt * 16 + l16;
                float vv = acc[mt][nt][r];
                if (bias)    vv += bias[gcol];
                if (do_relu) vv = vv > 0.f ? vv : 0.f;
                if (resid)   vv += resid[(size_t)grow * N + gcol];
                if (OUTF32) ((float*)Cp)[(size_t)grow * N + gcol] = vv;
                else        ((u16*)Cp)[(size_t)grow * N + gcol] = f2bf(vv);
            }
        }
    }
}

// QKV-fused variant: W stacked [3072 x 1024]; BN=128 divides 1024.
__global__ __launch_bounds__(512, 4) void gemm128q_qkv(
    const u16* __restrict__ A, const u16* __restrict__ Wqkv,
    u16* __restrict__ qo, u16* __restrict__ ko, u16* __restrict__ vo, int K)
{
    __shared__ u16 smem[24576];
    int tid  = threadIdx.x;
    int lane = tid & 63, wave = tid >> 6;
    int quad = lane >> 4, l16 = lane & 15;
    int wm = wave >> 2, wn = wave & 3;
    const int row_a0 = blockIdx.x * 128, row_w0 = blockIdx.y * 128;
    f32x4 acc[4][2] = {};
    gemm128q_core(A, Wqkv, K, K, row_a0, row_w0, smem, acc);
    int seg = row_w0 >> 10;
    u16* dst = (seg == 0) ? qo : (seg == 1) ? ko : vo;
    int col0 = row_w0 & 1023;
#pragma unroll
    for (int mt = 0; mt < 4; ++mt) {
#pragma unroll
        for (int nt = 0; nt < 2; ++nt) {
#pragma unroll
            for (int r = 0; r < 4; ++r) {
                int grow = row_a0 + wm * 64 + mt * 16 + quad * 4 + r;
                int gcol = col0 + wn * 32 + nt * 16 + l16;
                dst[(size_t)grow * 1024 + gcol] = f2bf(acc[mt][nt][r]);
            }
        }
    }
}

// -------- MFMA flash attention v4: 32 q-rows/wave, 256-q blocks ---------------
// (unchanged — control; LDS-BW-bound, 131.5 us, conflicts 1.055e7)
__global__ __launch_bounds__(512, 4) void attn_kernel(
    const u16* __restrict__ Q, const u16* __restrict__ Km, const u16* __restrict__ Vm,
    const int* __restrict__ mask, u16* __restrict__ O)
{
    const int S = 2048, DM = 1024;
    const float C1 = 0.18033688f;      // 0.125 * log2(e)
    const float C0 = -11.541560f;      // -8 * log2(e)
    __shared__ u16 smem[35840];        // 71,680 B -> 2 blocks/CU
    u16* Ks0 = smem;                   // [64*64] swizzled 16B chunks
    u16* Ks1 = smem + 4096;
    u16* Vt0 = smem + 8192;            // [64][72]
    u16* Vt1 = smem + 12800;
    u16* Ps  = smem + 17408;           // [256][72] wave-private rows
    u16* Qs  = smem + 17408;           // alias: Qs dead before Ps written

    int qt = blockIdx.x, bh = blockIdx.y;
    int b = bh >> 4, h = bh & 15;
    int tid = threadIdx.x;
    int wave = tid >> 6, lane = tid & 63;
    int quad = lane >> 4, l16 = lane & 15;
    size_t base = (size_t)b * S;
    size_t hoff = (size_t)h * 64;

    {   // stage Q tile [256 q][64 d]: 32 u16 per thread
        int r = tid >> 1, c0 = (tid & 1) * 32;
        const u16* src = Q + (base + qt * 256 + r) * DM + hoff + c0;
        u16* dq = Qs + r * 72 + c0;
        *(u16x8*)(dq)      = *(const u16x8*)(src);
        *(u16x8*)(dq + 8)  = *(const u16x8*)(src + 8);
        *(u16x8*)(dq + 16) = *(const u16x8*)(src + 16);
        *(u16x8*)(dq + 24) = *(const u16x8*)(src + 24);
    }
    const u16* ksrc = Km + (base + (tid >> 3)) * DM + hoff
                    + ((tid & 7) ^ ((tid >> 5) & 7)) * 8;
    int kp = tid & 31, d0 = (tid >> 5) * 4;
    const u16* vsrc = Vm + (base + kp * 2) * DM + hoff + d0;
    const int* msrc = mask + b * S + 4 * l16;

    __syncthreads();
    const int q0 = wave * 32;
    bf16x8 qf00 = *(const bf16x8*)(&Qs[(q0 + l16) * 72 + quad * 8]);
    bf16x8 qf01 = *(const bf16x8*)(&Qs[(q0 + l16) * 72 + 32 + quad * 8]);
    bf16x8 qf10 = *(const bf16x8*)(&Qs[(q0 + 16 + l16) * 72 + quad * 8]);
    bf16x8 qf11 = *(const bf16x8*)(&Qs[(q0 + 16 + l16) * 72 + 32 + quad * 8]);
    const int swz = (l16 & 7) * 8;
    const int u0  = (quad * 8) ^ swz;

    {   // prologue: stage tile 0 into Ks0/Vt0
        u16x4 va = *(const u16x4*)(vsrc);
        u16x4 vb = *(const u16x4*)(vsrc + DM);
        gload_lds16(ksrc, Ks0 + tid * 8);
        ksrc += 64 * DM; vsrc += 64 * DM;
#pragma unroll
        for (int i = 0; i < 4; ++i) {
            uint32_t w = (uint32_t)va[i] | ((uint32_t)vb[i] << 16);
            *(uint32_t*)(&Vt0[(d0 + i) * 72 + kp * 2]) = w;
        }
    }
    __syncthreads();

    float l0[4] = {0.f, 0.f, 0.f, 0.f};
    float l1[4] = {0.f, 0.f, 0.f, 0.f};
    f32x4 o0[4] = {}, o1[4] = {};

    for (int it = 0; it < 32; ++it) {
        const u16* Kcur = (it & 1) ? Ks1 : Ks0;
        const u16* Vcur = (it & 1) ? Vt1 : Vt0;
        u16* Knxt = (it & 1) ? Ks0 : Ks1;
        u16* Vnxt = (it & 1) ? Vt0 : Vt1;
        const bool pfch = (it < 31);
        u16x4 va, vb;
        if (pfch) {
            va = *(const u16x4*)(vsrc);
            vb = *(const u16x4*)(vsrc + DM);
            gload_lds16(ksrc, Knxt + tid * 8);
            ksrc += 64 * DM; vsrc += 64 * DM;
        }
        f32x4 s0[4] = {}, s1[4] = {};
#pragma unroll
        for (int t = 0; t < 4; ++t) {
            const u16* krp = Kcur + (4 * l16 + t) * 64;
            bf16x8 kf0 = *(const bf16x8*)(krp + u0);
            bf16x8 kf1 = *(const bf16x8*)(krp + (u0 ^ 32));
            s0[t] = __builtin_amdgcn_mfma_f32_16x16x32_bf16(qf00, kf0, s0[t], 0, 0, 0);
            s0[t] = __builtin_amdgcn_mfma_f32_16x16x32_bf16(qf01, kf1, s0[t], 0, 0, 0);
            s1[t] = __builtin_amdgcn_mfma_f32_16x16x32_bf16(qf10, kf0, s1[t], 0, 0, 0);
            s1[t] = __builtin_amdgcn_mfma_f32_16x16x32_bf16(qf11, kf1, s1[t], 0, 0, 0);
        }
        int4 mk4 = *(const int4*)(msrc); msrc += 64;
        float c0t[4];
        c0t[0] = (mk4.x == 0) ? -1e38f : C0;
        c0t[1] = (mk4.y == 0) ? -1e38f : C0;
        c0t[2] = (mk4.z == 0) ? -1e38f : C0;
        c0t[3] = (mk4.w == 0) ? -1e38f : C0;
#pragma unroll
        for (int r = 0; r < 4; ++r) {
            float p0 = exp2f(fmaf(s0[0][r], C1, c0t[0]));
            float p1 = exp2f(fmaf(s0[1][r], C1, c0t[1]));
            float p2 = exp2f(fmaf(s0[2][r], C1, c0t[2]));
            float p3 = exp2f(fmaf(s0[3][r], C1, c0t[3]));
            l0[r] += (p0 + p1) + (p2 + p3);
            uint2 pw;
            pw.x = cvt_pk_bf16(p0, p1);
            pw.y = cvt_pk_bf16(p2, p3);
            *(uint2*)(&Ps[(q0 + quad * 4 + r) * 72 + 4 * l16]) = pw;
        }
#pragma unroll
        for (int r = 0; r < 4; ++r) {
            float p0 = exp2f(fmaf(s1[0][r], C1, c0t[0]));
            float p1 = exp2f(fmaf(s1[1][r], C1, c0t[1]));
            float p2 = exp2f(fmaf(s1[2][r], C1, c0t[2]));
            float p3 = exp2f(fmaf(s1[3][r], C1, c0t[3]));
            l1[r] += (p0 + p1) + (p2 + p3);
            uint2 pw;
            pw.x = cvt_pk_bf16(p0, p1);
            pw.y = cvt_pk_bf16(p2, p3);
            *(uint2*)(&Ps[(q0 + 16 + quad * 4 + r) * 72 + 4 * l16]) = pw;
        }
        bf16x8 pf00 = *(const bf16x8*)(&Ps[(q0 + l16) * 72 + quad * 8]);
        bf16x8 pf01 = *(const bf16x8*)(&Ps[(q0 + l16) * 72 + 32 + quad * 8]);
        bf16x8 pf10 = *(const bf16x8*)(&Ps[(q0 + 16 + l16) * 72 + quad * 8]);
        bf16x8 pf11 = *(const bf16x8*)(&Ps[(q0 + 16 + l16) * 72 + 32 + quad * 8]);
#pragma unroll
        for (int t = 0; t < 4; ++t) {
            bf16x8 vf0 = *(const bf16x8*)(&Vcur[(t * 16 + l16) * 72 + quad * 8]);
            bf16x8 vf1 = *(const bf16x8*)(&Vcur[(t * 16 + l16) * 72 + 32 + quad * 8]);
            o0[t] = __builtin_amdgcn_mfma_f32_16x16x32_bf16(pf00, vf0, o0[t], 0, 0, 0);
            o0[t] = __builtin_amdgcn_mfma_f32_16x16x32_bf16(pf01, vf1, o0[t], 0, 0, 0);
            o1[t] = __builtin_amdgcn_mfma_f32_16x16x32_bf16(pf10, vf0, o1[t], 0, 0, 0);
            o1[t] = __builtin_amdgcn_mfma_f32_16x16x32_bf16(pf11, vf1, o1[t], 0, 0, 0);
        }
        if (pfch) {
#pragma unroll
            for (int i = 0; i < 4; ++i) {
                uint32_t w = (uint32_t)va[i] | ((uint32_t)vb[i] << 16);
                *(uint32_t*)(&Vnxt[(d0 + i) * 72 + kp * 2]) = w;
            }
        }
        __syncthreads();
    }
#pragma unroll
    for (int r = 0; r < 4; ++r) {
#pragma unroll
        for (int off = 1; off < 16; off <<= 1) {
            l0[r] += __shfl_xor(l0[r], off, 16);
            l1[r] += __shfl_xor(l1[r], off, 16);
        }
        float i0 = 1.0f / l0[r];
        float i1 = 1.0f / l1[r];
        u16* dst0 = O + (base + qt * 256 + q0 + quad * 4 + r) * DM + hoff + l16;
        u16* dst1 = dst0 + (size_t)16 * DM;
#pragma unroll
        for (int t = 0; t < 4; ++t) {
            dst0[t * 16] = f2bf(o0[t][r] * i0);
            dst1[t * 16] = f2bf(o1[t][r] * i1);
        }
    }
}

// -------------------------------------------------------------------------------
// Workspace budget: 72 MB (proven). ws[0..6)MB wq|wk|wv stacked; ws[6..8) wo;
// ws[8..24) w1,w2; ws[24..40) xn; ws[40..56) q; ws[40..72) hb.
// d_out doubles as k/v (bf16) then x1 (fp32).
extern "C" void kernel_launch(void* const* d_in, const int* in_sizes, int n_in,
                              void* d_out, int out_size, void* d_ws, size_t ws_size,
                              hipStream_t stream)
{
    (void)in_sizes; (void)n_in; (void)out_size; (void)ws_size;
    const float* x    = (const float*)d_in[0];
    const int*   mask = (const int*)d_in[1];
    const float* wq   = (const float*)d_in[2];
    const float* wk   = (const float*)d_in[3];
    const float* wv   = (const float*)d_in[4];
    const float* wo   = (const float*)d_in[5];
    const float* ln1a = (const float*)d_in[6];
    const float* ln1b = (const float*)d_in[7];
    const float* ln2a = (const float*)d_in[8];
    const float* ln2b = (const float*)d_in[9];
    const float* w1   = (const float*)d_in[10];
    const float* b1   = (const float*)d_in[11];
    const float* w2   = (const float*)d_in[12];
    const float* b2   = (const float*)d_in[13];

    const int M = 8192, D = 1024, F = 4096;
    char* ws = (char*)d_ws;
    u16*  wqkv = (u16*)(ws);                  // stacked 3072x1024
    u16*  wqb = wqkv;
    u16*  wkb = (u16*)(ws + (2u  << 20));
    u16*  wvb = (u16*)(ws + (4u  << 20));
    u16*  wob = (u16*)(ws + (6u  << 20));
    u16*  w1b = (u16*)(ws + (8u  << 20));
    u16*  w2b = (u16*)(ws + (16u << 20));
    u16*  xn  = (u16*)(ws + (24u << 20));     // xn1 / attn_out / xn2
    u16*  q   = (u16*)(ws + (40u << 20));
    u16*  hb  = (u16*)(ws + (40u << 20));     // overlaps q (q dead by FF1)

    u16*   kbuf = (u16*)d_out;
    u16*   vbuf = (u16*)d_out + (size_t)M * D;
    float* x1   = (float*)d_out;

    cvt_all<<<12288, 256, 0, stream>>>(wq, wk, wv, wo, w1, w2,
                                       wqb, wkb, wvb, wob, w1b, w2b);

    ln_kernel<<<M / 4, 256, 0, stream>>>(x, ln1a, ln1b, xn);
    dim3 gq(M / 128, 3072 / 128);             // 64 x 24 = 1536 (3 full rounds)
    gemm128q_qkv<<<gq, 512, 0, stream>>>(xn, wqkv, q, kbuf, vbuf, D);
    dim3 ga(2048 / 256, 64);
    attn_kernel<<<ga, 512, 0, stream>>>(q, kbuf, vbuf, mask, xn);
    dim3 g1(M / 128, D / 128);                // 64 x 8 = 512 (1 full round)
    gemm128q<true ><<<g1, 512, 0, stream>>>(xn, wob, nullptr, x, x1, M, D, D, D, 0);
    ln_kernel<<<M / 4, 256, 0, stream>>>(x1, ln2a, ln2b, xn);
    dim3 gf1(M / 128, 2048 / 128);            // 64 x 16 = 1024 (2 full rounds)
    dim3 gf2(M / 128, D / 128);               // 64 x 8 = 512 (1 full round)
    gemm128q<false><<<gf1, 512, 0, stream>>>(xn, w1b, b1, nullptr, hb, M, 2048, D, D, 1);
    gemm128q<true ><<<gf2, 512, 0, stream>>>(hb, w2b, nullptr, x1, x1, M, D, 2048, F, 0);
    gemm128q<false><<<gf1, 512, 0, stream>>>(xn, w1b + (size_t)2048 * D, b1 + 2048, nullptr, hb, M, 2048, D, D, 1);
    gemm128q<true ><<<gf2, 512, 0, stream>>>(hb, w2b + 2048, b2, x1, x1, M, D, 2048, F, 0);
}